// Round 1
// baseline (626.410 us; speedup 1.0000x reference)
//
#include <hip/hip_runtime.h>

#define N_ROWS 131072
#define DIM 64
#define KNEG 1024
#define FEPS 1e-10f
#define LOG2E 1.4426950408889634f

// ---------------------------------------------------------------------------
// Prep kernel: gather e_neg rows into contiguous ws, precompute
// lqk[c] = log(q_c + eps) * log2(e), G = max_c(-log(q_c+eps)) + margin,
// and zero the accumulators.
// ---------------------------------------------------------------------------
__global__ __launch_bounds__(1024) void prep_k(
    const float* __restrict__ emb, const int* __restrict__ sidx,
    const float* __restrict__ probs,
    float* __restrict__ eneg, float* __restrict__ lqk,
    float* __restrict__ gv, double* __restrict__ acc)
{
    const int tid = threadIdx.x;
    // gather e_neg: KNEG rows x DIM floats (coalesced: consecutive tid -> consecutive k)
    for (int e = tid; e < KNEG * DIM; e += 1024) {
        const int c = e >> 6;
        const int k = e & 63;
        eneg[e] = emb[(size_t)sidx[c] * DIM + k];
    }
    __shared__ float red[1024];
    float L = logf(probs[sidx[tid]] + FEPS);
    lqk[tid] = L * LOG2E;
    red[tid] = -L;
    __syncthreads();
    for (int s2 = 512; s2 > 0; s2 >>= 1) {
        if (tid < s2) red[tid] = fmaxf(red[tid], red[tid + s2]);
        __syncthreads();
    }
    if (tid == 0) {
        gv[0] = red[0] + 2.0f;   // upper-bound-ish M for negatives; exact math for any M
        acc[0] = 0.0;
        acc[1] = 0.0;
    }
}

// ---------------------------------------------------------------------------
// Main kernel: one row per thread. Hidden row in registers; e_neg read through
// wave-uniform addresses (scalar loads). Fixed-M logsumexp: exactly
//   lse = M + log( exp(pos-M) + sum_c exp(l_c - M) )   for any M.
// ---------------------------------------------------------------------------
__global__ __launch_bounds__(256) void main_k(
    const float* __restrict__ hidden, const int* __restrict__ y,
    const int* __restrict__ sidx, const float* __restrict__ emb,
    const float* __restrict__ probs,
    const float* __restrict__ eneg, const float* __restrict__ lqk,
    const float* __restrict__ gv, double* __restrict__ acc)
{
    const int n = blockIdx.x * 256 + threadIdx.x;
    const int yv = y[n];

    // hidden row -> registers
    float h[DIM];
    const float4* hp = (const float4*)(hidden + (size_t)n * DIM);
#pragma unroll
    for (int i = 0; i < DIM / 4; ++i) {
        float4 v = hp[i];
        h[4 * i + 0] = v.x; h[4 * i + 1] = v.y;
        h[4 * i + 2] = v.z; h[4 * i + 3] = v.w;
    }

    // positive logit: dot(hidden, emb[yv])
    const float4* ep = (const float4*)(emb + (size_t)yv * DIM);
    float pd0 = 0.f, pd1 = 0.f, pd2 = 0.f, pd3 = 0.f;
#pragma unroll
    for (int i = 0; i < DIM / 4; ++i) {
        float4 v = ep[i];
        pd0 = fmaf(h[4 * i + 0], v.x, pd0);
        pd1 = fmaf(h[4 * i + 1], v.y, pd1);
        pd2 = fmaf(h[4 * i + 2], v.z, pd2);
        pd3 = fmaf(h[4 * i + 3], v.w, pd3);
    }
    const float posdot = (pd0 + pd1) + (pd2 + pd3);
    const float pos = posdot - logf(probs[yv] + FEPS);

    const float G = gv[0];
    const float M = fmaxf(G, pos);
    const float mk = -M * LOG2E;          // fold M into exp2 argument

    float s = exp2f((pos - M) * LOG2E);

#pragma unroll 2
    for (int c = 0; c < KNEG; ++c) {
        const float* er = eneg + c * DIM;   // wave-uniform address -> s_load
        float d0 = 0.f, d1 = 0.f, d2 = 0.f, d3 = 0.f;
#pragma unroll
        for (int k = 0; k < DIM / 4; ++k) {
            d0 = fmaf(h[4 * k + 0], er[4 * k + 0], d0);
            d1 = fmaf(h[4 * k + 1], er[4 * k + 1], d1);
            d2 = fmaf(h[4 * k + 2], er[4 * k + 2], d2);
            d3 = fmaf(h[4 * k + 3], er[4 * k + 3], d3);
        }
        const float d = (d0 + d1) + (d2 + d3);
        // exp2 argument: (d - lq_c - M) * log2(e) = d*log2e - lqk_c + mk
        float e = fmaf(d, LOG2E, mk) - lqk[c];
        e = (yv == sidx[c]) ? -1.0e9f : e;  // collision -> contributes 0
        s += exp2f(e);
    }

    const float ce = M + logf(s) - pos;
    float w = (yv != 0) ? 1.0f : 0.0f;
    float v = ce * w;

    // wave (64-lane) reduction, then one atomic per wave
#pragma unroll
    for (int off = 32; off > 0; off >>= 1) {
        v += __shfl_down(v, off, 64);
        w += __shfl_down(w, off, 64);
    }
    if ((threadIdx.x & 63) == 0) {
        atomicAdd(&acc[0], (double)v);
        atomicAdd(&acc[1], (double)w);
    }
}

__global__ void fin_k(const double* __restrict__ acc, float* __restrict__ out)
{
    double c = acc[1];
    if (c < 1.0) c = 1.0;
    out[0] = (float)(acc[0] / c);
}

extern "C" void kernel_launch(void* const* d_in, const int* in_sizes, int n_in,
                              void* d_out, int out_size, void* d_ws, size_t ws_size,
                              hipStream_t stream) {
    const float* hidden = (const float*)d_in[0];
    const int*   yv     = (const int*)d_in[1];
    const int*   sidx   = (const int*)d_in[2];
    const float* emb    = (const float*)d_in[3];
    const float* probs  = (const float*)d_in[4];
    float* out = (float*)d_out;

    char* ws = (char*)d_ws;
    float*  eneg = (float*)(ws);             // 1024*64*4 = 262144 B
    float*  lqk  = (float*)(ws + 262144);    // 1024*4   =   4096 B
    float*  gv   = (float*)(ws + 266240);    //               8 B (padded)
    double* acc  = (double*)(ws + 266248);   //              16 B (8-aligned)

    prep_k<<<1, 1024, 0, stream>>>(emb, sidx, probs, eneg, lqk, gv, acc);
    main_k<<<N_ROWS / 256, 256, 0, stream>>>(hidden, yv, sidx, emb, probs,
                                             eneg, lqk, gv, acc);
    fin_k<<<1, 1, 0, stream>>>(acc, out);
}

// Round 2
// 90.174 us; speedup vs baseline: 6.9467x; 6.9467x over previous
//
#include <hip/hip_runtime.h>

#define N_ROWS 131072
#define DIM 64
#define KNEG 1024
#define FEPS 1e-10f
#define LOG2E 1.4426950408889634f
#define HSLOTS 2048

typedef __attribute__((ext_vector_type(8))) short bf16x8;
typedef __attribute__((ext_vector_type(4))) float f32x4;

__device__ __forceinline__ unsigned short f2bf(float x) {
    unsigned int u = __float_as_uint(x);
    unsigned int r = (u + 0x7fffu + ((u >> 16) & 1u)) >> 16;
    return (unsigned short)r;
}

// ---------------------------------------------------------------------------
// gather_k: enegPK[col][k] = bf16(emb[sidx[col]][k]), 128B per col, 64 blocks.
// ---------------------------------------------------------------------------
__global__ __launch_bounds__(256) void gather_k(
    const float* __restrict__ emb, const int* __restrict__ sidx,
    unsigned short* __restrict__ enegPK)
{
    const int gid = blockIdx.x * 256 + threadIdx.x;   // 0..16383
    const int col = gid >> 4;
    const int j   = gid & 15;                          // 16B chunk within row
    const int c = sidx[col];
    const float4 v = *(const float4*)(emb + (size_t)c * DIM + j * 4);
    unsigned int lo = (unsigned int)f2bf(v.x) | ((unsigned int)f2bf(v.y) << 16);
    unsigned int hi = (unsigned int)f2bf(v.z) | ((unsigned int)f2bf(v.w) << 16);
    ((uint2*)enegPK)[(size_t)col * 16 + j] = make_uint2(lo, hi);
}

// ---------------------------------------------------------------------------
// scal_k: G = max_c(-log(q_c+eps)) + 2;  f[c] = exp(-log(q_c+eps) - G);
// hash table y -> sum of colliding f_c.  Single block, 1024 threads.
// ---------------------------------------------------------------------------
__global__ __launch_bounds__(1024) void scal_k(
    const int* __restrict__ sidx, const float* __restrict__ probs,
    float* __restrict__ f, float* __restrict__ gv,
    int* __restrict__ hkey, float* __restrict__ hval)
{
    const int tid = threadIdx.x;
    for (int s = tid; s < HSLOTS; s += 1024) { hkey[s] = -1; hval[s] = 0.0f; }

    const int c = sidx[tid];
    const float L = logf(probs[c] + FEPS);

    __shared__ float red[1024];
    red[tid] = -L;
    __syncthreads();
    for (int s2 = 512; s2 > 0; s2 >>= 1) {
        if (tid < s2) red[tid] = fmaxf(red[tid], red[tid + s2]);
        __syncthreads();
    }
    const float G = red[0] + 2.0f;
    if (tid == 0) gv[0] = G;

    const float fc = exp2f((-L - G) * LOG2E);
    f[tid] = fc;

    // hash insert (linear probing)
    unsigned int slot = ((unsigned int)c * 2654435761u) & (HSLOTS - 1);
    for (int it = 0; it < HSLOTS; ++it) {
        int old = atomicCAS(&hkey[slot], -1, c);
        if (old == -1 || old == c) { atomicAdd(&hval[slot], fc); break; }
        slot = (slot + 1) & (HSLOTS - 1);
    }
}

// ---------------------------------------------------------------------------
// main_k: 4 waves/block, 16 rows/wave, full K=1024 cols via 64 tiles of 16.
//   acc = mfma(h_frag, b_frag) over D=64 (2 MFMAs), term = exp2(acc)*f[col],
//   per-row sums reduced across lanes; epilogue does pos logit, collision
//   correction, ce, and per-wave partial writes.
// ---------------------------------------------------------------------------
__global__ __launch_bounds__(256) void main_k(
    const float* __restrict__ hidden, const int* __restrict__ y,
    const float* __restrict__ emb, const float* __restrict__ probs,
    const unsigned short* __restrict__ enegPK, const float* __restrict__ f,
    const float* __restrict__ gv, const int* __restrict__ hkey,
    const float* __restrict__ hval,
    float* __restrict__ pv, float* __restrict__ pw)
{
    __shared__ __align__(16) short bt[2][16 * 72];   // 16 cols x 144B (padded)
    __shared__ float f_lds[KNEG];

    const int tid  = threadIdx.x;
    const int wid  = tid >> 6;
    const int lane = tid & 63;
    const int quad = lane >> 4;
    const int l15  = lane & 15;

    const int row0 = (blockIdx.x * 4 + wid) * 16;
    const int arow = row0 + l15;

    const int yr = y[arow];                     // per (lane&15) row

    // hidden row fragment: 16 f32, k = quad*8 + i  (+32 for second half)
    const float* hp = hidden + (size_t)arow * DIM + quad * 8;
    const float4 a0 = *(const float4*)(hp + 0);
    const float4 a1 = *(const float4*)(hp + 4);
    const float4 a2 = *(const float4*)(hp + 32);
    const float4 a3 = *(const float4*)(hp + 36);
    float h32[16] = {a0.x, a0.y, a0.z, a0.w, a1.x, a1.y, a1.z, a1.w,
                     a2.x, a2.y, a2.z, a2.w, a3.x, a3.y, a3.z, a3.w};
    bf16x8 h0, h1;
#pragma unroll
    for (int i = 0; i < 8; ++i) {
        h0[i] = (short)f2bf(h32[i] * LOG2E);
        h1[i] = (short)f2bf(h32[8 + i] * LOG2E);
    }

    // stage f[] into LDS
    for (int i = tid; i < KNEG; i += 256) f_lds[i] = f[i];

    // stage B tile 0
    const uint2* gsrc = (const uint2*)enegPK;   // 16 uint2 per col
    {
        uint2 s0 = gsrc[tid];
        ((uint2*)&bt[0][(tid >> 4) * 72])[tid & 15] = s0;
    }
    __syncthreads();

    float s0 = 0.f, s1 = 0.f, s2 = 0.f, s3 = 0.f;
    int p = 0;
    const short* myb = &bt[0][0] + l15 * 72 + quad * 8;

    for (int t = 0; t < KNEG / 16; ++t) {
        uint2 stg;
        const bool has = (t + 1 < KNEG / 16);
        if (has) stg = gsrc[(t + 1) * 256 + tid];

        const float fc = f_lds[t * 16 + l15];
        const short* bp = myb + p * (16 * 72);
        const bf16x8 b0 = *(const bf16x8*)(bp);
        const bf16x8 b1 = *(const bf16x8*)(bp + 32);

        f32x4 acc = {0.f, 0.f, 0.f, 0.f};
        acc = __builtin_amdgcn_mfma_f32_16x16x32_bf16(h0, b0, acc, 0, 0, 0);
        acc = __builtin_amdgcn_mfma_f32_16x16x32_bf16(h1, b1, acc, 0, 0, 0);

        s0 = fmaf(exp2f(acc[0]), fc, s0);
        s1 = fmaf(exp2f(acc[1]), fc, s1);
        s2 = fmaf(exp2f(acc[2]), fc, s2);
        s3 = fmaf(exp2f(acc[3]), fc, s3);

        if (has) ((uint2*)&bt[p ^ 1][(tid >> 4) * 72])[tid & 15] = stg;
        __syncthreads();
        p ^= 1;
    }

    // positive logit dot (f32): e_pos elements matching this lane's k-range
    const float* pe = emb + (size_t)yr * DIM + quad * 8;
    const float4 e0 = *(const float4*)(pe + 0);
    const float4 e1 = *(const float4*)(pe + 4);
    const float4 e2 = *(const float4*)(pe + 32);
    const float4 e3 = *(const float4*)(pe + 36);
    float pd = h32[0] * e0.x + h32[1] * e0.y + h32[2] * e0.z + h32[3] * e0.w
             + h32[4] * e1.x + h32[5] * e1.y + h32[6] * e1.z + h32[7] * e1.w
             + h32[8] * e2.x + h32[9] * e2.y + h32[10] * e2.z + h32[11] * e2.w
             + h32[12] * e3.x + h32[13] * e3.y + h32[14] * e3.z + h32[15] * e3.w;
    pd += __shfl_xor(pd, 16, 64);
    pd += __shfl_xor(pd, 32, 64);               // full posdot for row l15

    // sum-exp per row: reduce the 16 lanes of each quad (cols)
#pragma unroll
    for (int m = 8; m > 0; m >>= 1) {
        s0 += __shfl_xor(s0, m, 64);
        s1 += __shfl_xor(s1, m, 64);
        s2 += __shfl_xor(s2, m, 64);
        s3 += __shfl_xor(s3, m, 64);
    }
    // gather row (lane&15)'s sum: src quad = (l15>>2), src reg = (l15&3)
    float sa = (lane & 1) ? s1 : s0;
    float sb = (lane & 1) ? s3 : s2;
    float sv = (lane & 2) ? sb : sa;
    sv = __shfl(sv, ((l15 >> 2) << 4) + l15, 64);

    // epilogue (all lanes compute; quads duplicate, lane0 writes)
    const float G  = gv[0];
    const float qy = probs[yr];
    const float pos = pd - logf(qy + FEPS);

    float H = 0.0f;
    unsigned int slot = ((unsigned int)yr * 2654435761u) & (HSLOTS - 1);
    for (int it = 0; it < HSLOTS; ++it) {
        const int k = hkey[slot];
        if (k == yr) { H = hval[slot]; break; }
        if (k == -1) break;
        slot = (slot + 1) & (HSLOTS - 1);
    }
    float sneg = sv - exp2f(pd * LOG2E) * H;    // remove collision terms
    sneg = fmaxf(sneg, 0.0f);

    const float M = fmaxf(G, pos);
    const float lse = M + logf(exp2f((pos - M) * LOG2E) +
                               sneg * exp2f((G - M) * LOG2E));
    const float w = (yr != 0) ? 1.0f : 0.0f;
    float v = (lse - pos) * w;
    float ww = w;
#pragma unroll
    for (int m = 8; m > 0; m >>= 1) {
        v  += __shfl_xor(v, m, 64);
        ww += __shfl_xor(ww, m, 64);
    }
    // lanes 0,16,32,48 hold the same 16-row sums; lane 0 writes
    if (lane == 0) {
        const int wgid = blockIdx.x * 4 + wid;
        pv[wgid] = v;
        pw[wgid] = ww;
    }
}

__global__ __launch_bounds__(256) void fin_k(
    const float* __restrict__ pv, const float* __restrict__ pw,
    float* __restrict__ out)
{
    const int tid = threadIdx.x;
    double av = 0.0, aw = 0.0;
    for (int i = tid; i < N_ROWS / 16; i += 256) { av += pv[i]; aw += pw[i]; }
    __shared__ double rv[256], rw[256];
    rv[tid] = av; rw[tid] = aw;
    __syncthreads();
    for (int s2 = 128; s2 > 0; s2 >>= 1) {
        if (tid < s2) { rv[tid] += rv[tid + s2]; rw[tid] += rw[tid + s2]; }
        __syncthreads();
    }
    if (tid == 0) {
        double c = rw[0] < 1.0 ? 1.0 : rw[0];
        out[0] = (float)(rv[0] / c);
    }
}

extern "C" void kernel_launch(void* const* d_in, const int* in_sizes, int n_in,
                              void* d_out, int out_size, void* d_ws, size_t ws_size,
                              hipStream_t stream) {
    const float* hidden = (const float*)d_in[0];
    const int*   yv     = (const int*)d_in[1];
    const int*   sidx   = (const int*)d_in[2];
    const float* emb    = (const float*)d_in[3];
    const float* probs  = (const float*)d_in[4];
    float* out = (float*)d_out;

    char* ws = (char*)d_ws;
    unsigned short* enegPK = (unsigned short*)(ws);          // 131072 B
    float* f    = (float*)(ws + 131072);                     //   4096 B
    float* gv   = (float*)(ws + 135168);                     //    256 B
    int*   hkey = (int*)(ws + 135424);                       //   8192 B
    float* hval = (float*)(ws + 143616);                     //   8192 B
    float* pv   = (float*)(ws + 151808);                     //  32768 B
    float* pw   = (float*)(ws + 184576);                     //  32768 B

    gather_k<<<64, 256, 0, stream>>>(emb, sidx, enegPK);
    scal_k<<<1, 1024, 0, stream>>>(sidx, probs, f, gv, hkey, hval);
    main_k<<<N_ROWS / 64, 256, 0, stream>>>(hidden, yv, emb, probs, enegPK,
                                            f, gv, hkey, hval, pv, pw);
    fin_k<<<1, 256, 0, stream>>>(pv, pw, out);
}

// Round 3
// 59.880 us; speedup vs baseline: 10.4611x; 1.5059x over previous
//
#include <hip/hip_runtime.h>

#define N_ROWS 131072
#define DIM 64
#define KNEG 1024
#define FEPS 1e-10f
#define LOG2E 1.4426950408889634f
#define HSLOTS 2048
#define CPI 128                 // cols per outer iter
#define OUTER (KNEG / CPI)      // 8
#define CSTR 72                 // shorts per col in LDS (144 B padded)

typedef __attribute__((ext_vector_type(8))) short bf16x8;
typedef __attribute__((ext_vector_type(4))) float f32x4;

__device__ __forceinline__ unsigned short f2bf(float x) {
    unsigned int u = __float_as_uint(x);
    unsigned int r = (u + 0x7fffu + ((u >> 16) & 1u)) >> 16;
    return (unsigned short)r;
}

#if __has_builtin(__builtin_amdgcn_exp2f)
__device__ __forceinline__ float fexp2(float x) { return __builtin_amdgcn_exp2f(x); }
#else
__device__ __forceinline__ float fexp2(float x) {
    float r; asm("v_exp_f32 %0, %1\ns_nop 1" : "=v"(r) : "v"(x)); return r;
}
#endif

__device__ __forceinline__ bf16x8 cvt8(float4 u, float4 v) {
    bf16x8 r;
    r[0] = (short)f2bf(u.x * LOG2E); r[1] = (short)f2bf(u.y * LOG2E);
    r[2] = (short)f2bf(u.z * LOG2E); r[3] = (short)f2bf(u.w * LOG2E);
    r[4] = (short)f2bf(v.x * LOG2E); r[5] = (short)f2bf(v.y * LOG2E);
    r[6] = (short)f2bf(v.z * LOG2E); r[7] = (short)f2bf(v.w * LOG2E);
    return r;
}

// ---------------------------------------------------------------------------
// prep_k: blocks 0..15 gather e_neg -> bf16 packed [col][k]; block 16 computes
// G, lf[c] = (-log(q_c+eps)-G)*log2e, and the collision hash (y -> sum f_c).
// ---------------------------------------------------------------------------
__global__ __launch_bounds__(1024) void prep_k(
    const float* __restrict__ emb, const int* __restrict__ sidx,
    const float* __restrict__ probs,
    unsigned short* __restrict__ enegPK, float* __restrict__ lf,
    float* __restrict__ gv, int* __restrict__ hkey, float* __restrict__ hval)
{
    const int tid = threadIdx.x;
    if (blockIdx.x < 16) {
        const int gid = blockIdx.x * 1024 + tid;   // 0..16383
        const int col = gid >> 4;
        const int j   = gid & 15;
        const int c = sidx[col];
        const float4 v = *(const float4*)(emb + (size_t)c * DIM + j * 4);
        unsigned int lo = (unsigned int)f2bf(v.x) | ((unsigned int)f2bf(v.y) << 16);
        unsigned int hi = (unsigned int)f2bf(v.z) | ((unsigned int)f2bf(v.w) << 16);
        ((uint2*)enegPK)[(size_t)col * 16 + j] = make_uint2(lo, hi);
    } else {
        for (int s = tid; s < HSLOTS; s += 1024) { hkey[s] = -1; hval[s] = 0.0f; }
        const int c = sidx[tid];
        const float L = logf(probs[c] + FEPS);
        __shared__ float red[1024];
        red[tid] = -L;
        __syncthreads();
        for (int s2 = 512; s2 > 0; s2 >>= 1) {
            if (tid < s2) red[tid] = fmaxf(red[tid], red[tid + s2]);
            __syncthreads();
        }
        const float G = red[0] + 2.0f;
        if (tid == 0) gv[0] = G;
        const float lfv = (-L - G) * LOG2E;
        lf[tid] = lfv;
        const float fc = exp2f(lfv);
        unsigned int slot = ((unsigned int)c * 2654435761u) & (HSLOTS - 1);
        for (int it = 0; it < HSLOTS; ++it) {
            int old = atomicCAS(&hkey[slot], -1, c);
            if (old == -1 || old == c) { atomicAdd(&hval[slot], fc); break; }
            slot = (slot + 1) & (HSLOTS - 1);
        }
    }
}

// ---------------------------------------------------------------------------
// main_k: 4 waves/block, 32 rows/wave (2 MFMA row-panels), 128-col LDS tiles
// double-buffered. acc init = lf_col, so per element: 1 exp2 + 1 add.
// ---------------------------------------------------------------------------
__global__ __launch_bounds__(256, 4) void main_k(
    const float* __restrict__ hidden, const int* __restrict__ y,
    const float* __restrict__ emb, const float* __restrict__ probs,
    const unsigned short* __restrict__ enegPK, const float* __restrict__ lf,
    const float* __restrict__ gv, const int* __restrict__ hkey,
    const float* __restrict__ hval,
    float* __restrict__ pv, float* __restrict__ pw)
{
    __shared__ __align__(16) short bt[2][CPI * CSTR];   // 36864 B
    __shared__ float lf_lds[KNEG];                       //  4096 B

    const int tid  = threadIdx.x;
    const int wid  = tid >> 6;
    const int lane = tid & 63;
    const int quad = lane >> 4;
    const int l15  = lane & 15;

    const int row0 = (blockIdx.x * 4 + wid) * 32;
    const int r0 = row0 + l15;
    const int r1 = row0 + 16 + l15;

    const int y0 = y[r0];
    const int y1 = y[r1];

    // stage lf into LDS
    for (int i = tid; i < KNEG; i += 256) lf_lds[i] = lf[i];

    // preload B tile 0
    const uint4* g4 = (const uint4*)enegPK;       // 8192 uint4 (col-major, 8/col)
    const int cw = tid >> 3;                       // write col base (0..31)
    const int ow = tid & 7;
    {
        uint4 u0 = g4[tid], u1 = g4[tid + 256], u2 = g4[tid + 512], u3 = g4[tid + 768];
        short* dst = &bt[0][0];
        *((uint4*)(dst + (cw +  0) * CSTR) + ow) = u0;
        *((uint4*)(dst + (cw + 32) * CSTR) + ow) = u1;
        *((uint4*)(dst + (cw + 64) * CSTR) + ow) = u2;
        *((uint4*)(dst + (cw + 96) * CSTR) + ow) = u3;
    }

    // hidden rows (f32) for both panels
    const float* hp0 = hidden + (size_t)r0 * DIM + quad * 8;
    const float* hp1 = hidden + (size_t)r1 * DIM + quad * 8;
    const float4 a0 = *(const float4*)(hp0 + 0);
    const float4 a1 = *(const float4*)(hp0 + 4);
    const float4 a2 = *(const float4*)(hp0 + 32);
    const float4 a3 = *(const float4*)(hp0 + 36);
    const float4 c0 = *(const float4*)(hp1 + 0);
    const float4 c1 = *(const float4*)(hp1 + 4);
    const float4 c2 = *(const float4*)(hp1 + 32);
    const float4 c3 = *(const float4*)(hp1 + 36);

    // positive logit dots (f32)
    const float* pe0 = emb + (size_t)y0 * DIM + quad * 8;
    const float* pe1 = emb + (size_t)y1 * DIM + quad * 8;
    const float4 e0 = *(const float4*)(pe0 + 0);
    const float4 e1 = *(const float4*)(pe0 + 4);
    const float4 e2 = *(const float4*)(pe0 + 32);
    const float4 e3 = *(const float4*)(pe0 + 36);
    const float4 g0 = *(const float4*)(pe1 + 0);
    const float4 g1 = *(const float4*)(pe1 + 4);
    const float4 g2 = *(const float4*)(pe1 + 32);
    const float4 g3 = *(const float4*)(pe1 + 36);
    float pd0 = a0.x*e0.x + a0.y*e0.y + a0.z*e0.z + a0.w*e0.w
              + a1.x*e1.x + a1.y*e1.y + a1.z*e1.z + a1.w*e1.w
              + a2.x*e2.x + a2.y*e2.y + a2.z*e2.z + a2.w*e2.w
              + a3.x*e3.x + a3.y*e3.y + a3.z*e3.z + a3.w*e3.w;
    float pd1 = c0.x*g0.x + c0.y*g0.y + c0.z*g0.z + c0.w*g0.w
              + c1.x*g1.x + c1.y*g1.y + c1.z*g1.z + c1.w*g1.w
              + c2.x*g2.x + c2.y*g2.y + c2.z*g2.z + c2.w*g2.w
              + c3.x*g3.x + c3.y*g3.y + c3.z*g3.z + c3.w*g3.w;
    pd0 += __shfl_xor(pd0, 16, 64); pd0 += __shfl_xor(pd0, 32, 64);
    pd1 += __shfl_xor(pd1, 16, 64); pd1 += __shfl_xor(pd1, 32, 64);

    // bf16 fragments (scaled by log2e)
    const bf16x8 h00 = cvt8(a0, a1), h01 = cvt8(a2, a3);
    const bf16x8 h10 = cvt8(c0, c1), h11 = cvt8(c2, c3);

    __syncthreads();

    float s00 = 0.f, s01 = 0.f, s02 = 0.f, s03 = 0.f;
    float s10 = 0.f, s11 = 0.f, s12 = 0.f, s13 = 0.f;
    int p = 0;

    for (int t = 0; t < OUTER; ++t) {
        uint4 u0, u1, u2, u3;
        const bool has = (t + 1 < OUTER);
        if (has) {
            const uint4* gs = g4 + (t + 1) * 1024;
            u0 = gs[tid]; u1 = gs[tid + 256]; u2 = gs[tid + 512]; u3 = gs[tid + 768];
        }
#pragma unroll
        for (int tt = 0; tt < 8; ++tt) {
            const short* bp = &bt[p][(tt * 16 + l15) * CSTR + quad * 8];
            const bf16x8 b0 = *(const bf16x8*)bp;
            const bf16x8 b1 = *(const bf16x8*)(bp + 32);
            const float lfv = lf_lds[t * CPI + tt * 16 + l15];
            f32x4 acc0 = {lfv, lfv, lfv, lfv};
            acc0 = __builtin_amdgcn_mfma_f32_16x16x32_bf16(h00, b0, acc0, 0, 0, 0);
            acc0 = __builtin_amdgcn_mfma_f32_16x16x32_bf16(h01, b1, acc0, 0, 0, 0);
            f32x4 acc1 = {lfv, lfv, lfv, lfv};
            acc1 = __builtin_amdgcn_mfma_f32_16x16x32_bf16(h10, b0, acc1, 0, 0, 0);
            acc1 = __builtin_amdgcn_mfma_f32_16x16x32_bf16(h11, b1, acc1, 0, 0, 0);
            s00 += fexp2(acc0[0]); s01 += fexp2(acc0[1]);
            s02 += fexp2(acc0[2]); s03 += fexp2(acc0[3]);
            s10 += fexp2(acc1[0]); s11 += fexp2(acc1[1]);
            s12 += fexp2(acc1[2]); s13 += fexp2(acc1[3]);
        }
        __syncthreads();
        if (has) {
            short* dst = &bt[p ^ 1][0];
            *((uint4*)(dst + (cw +  0) * CSTR) + ow) = u0;
            *((uint4*)(dst + (cw + 32) * CSTR) + ow) = u1;
            *((uint4*)(dst + (cw + 64) * CSTR) + ow) = u2;
            *((uint4*)(dst + (cw + 96) * CSTR) + ow) = u3;
        }
        __syncthreads();
        p ^= 1;
    }

    // reduce col-sums across the 16 lanes of each quad
#pragma unroll
    for (int m = 8; m > 0; m >>= 1) {
        s00 += __shfl_xor(s00, m, 64); s01 += __shfl_xor(s01, m, 64);
        s02 += __shfl_xor(s02, m, 64); s03 += __shfl_xor(s03, m, 64);
        s10 += __shfl_xor(s10, m, 64); s11 += __shfl_xor(s11, m, 64);
        s12 += __shfl_xor(s12, m, 64); s13 += __shfl_xor(s13, m, 64);
    }
    // row (l15) sum lives in quad l15>>2, reg l15&3
    float sa0 = (lane & 1) ? s01 : s00;
    float sb0 = (lane & 1) ? s03 : s02;
    float sv0 = (lane & 2) ? sb0 : sa0;
    sv0 = __shfl(sv0, ((l15 >> 2) << 4) + l15, 64);
    float sa1 = (lane & 1) ? s11 : s10;
    float sb1 = (lane & 1) ? s13 : s12;
    float sv1 = (lane & 2) ? sb1 : sa1;
    sv1 = __shfl(sv1, ((l15 >> 2) << 4) + l15, 64);

    // epilogue (quads duplicate)
    const float G = gv[0];
    float v = 0.f, ww = 0.f;
    {
        const float pos = pd0 - logf(probs[y0] + FEPS);
        float H = 0.0f;
        unsigned int slot = ((unsigned int)y0 * 2654435761u) & (HSLOTS - 1);
        for (int it = 0; it < HSLOTS; ++it) {
            const int k = hkey[slot];
            if (k == y0) { H = hval[slot]; break; }
            if (k == -1) break;
            slot = (slot + 1) & (HSLOTS - 1);
        }
        float sneg = fmaxf(sv0 - exp2f(pd0 * LOG2E) * H, 0.0f);
        const float M = fmaxf(G, pos);
        const float lse = M + logf(exp2f((pos - M) * LOG2E) + sneg * exp2f((G - M) * LOG2E));
        const float w = (y0 != 0) ? 1.0f : 0.0f;
        v += (lse - pos) * w; ww += w;
    }
    {
        const float pos = pd1 - logf(probs[y1] + FEPS);
        float H = 0.0f;
        unsigned int slot = ((unsigned int)y1 * 2654435761u) & (HSLOTS - 1);
        for (int it = 0; it < HSLOTS; ++it) {
            const int k = hkey[slot];
            if (k == y1) { H = hval[slot]; break; }
            if (k == -1) break;
            slot = (slot + 1) & (HSLOTS - 1);
        }
        float sneg = fmaxf(sv1 - exp2f(pd1 * LOG2E) * H, 0.0f);
        const float M = fmaxf(G, pos);
        const float lse = M + logf(exp2f((pos - M) * LOG2E) + sneg * exp2f((G - M) * LOG2E));
        const float w = (y1 != 0) ? 1.0f : 0.0f;
        v += (lse - pos) * w; ww += w;
    }
#pragma unroll
    for (int m = 8; m > 0; m >>= 1) {
        v  += __shfl_xor(v, m, 64);
        ww += __shfl_xor(ww, m, 64);
    }
    if (lane == 0) {
        const int wgid = blockIdx.x * 4 + wid;
        pv[wgid] = v;
        pw[wgid] = ww;
    }
}

__global__ __launch_bounds__(256) void fin_k(
    const float* __restrict__ pv, const float* __restrict__ pw,
    float* __restrict__ out)
{
    const int tid = threadIdx.x;
    double av = 0.0, aw = 0.0;
    for (int i = tid; i < N_ROWS / 32; i += 256) { av += pv[i]; aw += pw[i]; }
    __shared__ double rv[256], rw[256];
    rv[tid] = av; rw[tid] = aw;
    __syncthreads();
    for (int s2 = 128; s2 > 0; s2 >>= 1) {
        if (tid < s2) { rv[tid] += rv[tid + s2]; rw[tid] += rw[tid + s2]; }
        __syncthreads();
    }
    if (tid == 0) {
        double c = rw[0] < 1.0 ? 1.0 : rw[0];
        out[0] = (float)(rv[0] / c);
    }
}

extern "C" void kernel_launch(void* const* d_in, const int* in_sizes, int n_in,
                              void* d_out, int out_size, void* d_ws, size_t ws_size,
                              hipStream_t stream) {
    const float* hidden = (const float*)d_in[0];
    const int*   yv     = (const int*)d_in[1];
    const int*   sidx   = (const int*)d_in[2];
    const float* emb    = (const float*)d_in[3];
    const float* probs  = (const float*)d_in[4];
    float* out = (float*)d_out;

    char* ws = (char*)d_ws;
    unsigned short* enegPK = (unsigned short*)(ws);          // 131072 B
    float* lf   = (float*)(ws + 131072);                     //   4096 B
    float* gv   = (float*)(ws + 135168);                     //    256 B
    int*   hkey = (int*)(ws + 135424);                       //   8192 B
    float* hval = (float*)(ws + 143616);                     //   8192 B
    float* pv   = (float*)(ws + 151808);                     //  16384 B
    float* pw   = (float*)(ws + 168192);                     //  16384 B

    prep_k<<<17, 1024, 0, stream>>>(emb, sidx, probs, enegPK, lf, gv, hkey, hval);
    main_k<<<N_ROWS / 128, 256, 0, stream>>>(hidden, yv, emb, probs, enegPK,
                                             lf, gv, hkey, hval, pv, pw);
    fin_k<<<1, 256, 0, stream>>>(pv, pw, out);
}